// Round 1
// baseline (1947.953 us; speedup 1.0000x reference)
//
#include <hip/hip_runtime.h>
#include <hip/hip_bf16.h>

#define NN 4096
#define NE 131072
#define CH 256
#define KSEL 2048

typedef __hip_bfloat16 bf16;

// ---------- build dense A (f32 counts) + row degree d1 ----------
__global__ void build_A(const int* __restrict__ ei, float* __restrict__ Af,
                        float* __restrict__ d1) {
    int e = blockIdx.x * blockDim.x + threadIdx.x;
    if (e < NE) {
        int r = ei[e];
        int c = ei[NE + e];
        atomicAdd(&Af[(size_t)r * NN + c], 1.0f);
        atomicAdd(&d1[r], 1.0f);
    }
}

// ---------- convert A to bf16 (entries are small ints -> exact) ----------
__global__ void convert_A(const float* __restrict__ Af, bf16* __restrict__ Ab) {
    size_t i = ((size_t)blockIdx.x * blockDim.x + threadIdx.x) * 4;
    float4 v = *reinterpret_cast<const float4*>(Af + i);
    union { bf16 b[4]; ushort4 u; } cvt;
    cvt.b[0] = __float2bfloat16(v.x);
    cvt.b[1] = __float2bfloat16(v.y);
    cvt.b[2] = __float2bfloat16(v.z);
    cvt.b[3] = __float2bfloat16(v.w);
    *reinterpret_cast<ushort4*>(Ab + i) = cvt.u;
}

// ---------- sparse matvec via edge list: vout[row] += vin[col] ----------
__global__ void spmv_edge(const int* __restrict__ ei, const float* __restrict__ vin,
                          float* __restrict__ vout) {
    int e = blockIdx.x * blockDim.x + threadIdx.x;
    if (e < NE) atomicAdd(&vout[ei[e]], vin[ei[NE + e]]);
}

// ---------- score = tanh(pw0 * (x . transform) + pw1 * degree) ----------
__global__ void score_kernel(const float* __restrict__ x, const float* __restrict__ tr,
                             const float* __restrict__ d1, const float* __restrict__ d2,
                             const float* __restrict__ d3, const float* __restrict__ fw,
                             const float* __restrict__ pw, float* __restrict__ score) {
    int gtid = blockIdx.x * blockDim.x + threadIdx.x;
    int node = gtid >> 6;
    int lane = gtid & 63;
    if (node >= NN) return;
    const float* xr = x + (size_t)node * CH;
    float s = 0.f;
    #pragma unroll
    for (int q = 0; q < CH; q += 64) s += xr[q + lane] * tr[q + lane];
    #pragma unroll
    for (int off = 32; off > 0; off >>= 1) s += __shfl_down(s, off);
    if (lane == 0) {
        float deg = fw[0] + fw[1] * d1[node] + fw[2] * d2[node] + fw[3] * d3[node];
        score[node] = tanhf(pw[0] * s + pw[1] * deg);
    }
}

// ---------- stable descending argsort via O(N^2) rank; top-KSEL ----------
// rank[i] = #{j : s[j] > s[i]} + #{j < i : s[j] == s[i]}  (== jnp stable argsort(-s))
__global__ void rank_kernel(const float* __restrict__ score, int* __restrict__ perm,
                            float* __restrict__ score_perm, float* __restrict__ out_perm,
                            float* __restrict__ out_score) {
    int i = blockIdx.x * blockDim.x + threadIdx.x;
    if (i >= NN) return;
    float si = score[i];
    int r = 0;
    for (int j = 0; j < NN; j++) {
        float sj = score[j];
        r += (int)((sj > si) | ((sj == si) & (j < i)));
    }
    if (r < KSEL) {
        perm[r] = i;
        score_perm[r] = si;
        out_perm[r] = (float)i;
        out_score[r] = si;
    }
}

// ---------- B = A[:, perm]  (bf16, 4096 x 2048) ----------
__global__ void gather_cols(const bf16* __restrict__ Ab, const int* __restrict__ perm,
                            bf16* __restrict__ Bb) {
    int idx = blockIdx.x * blockDim.x + threadIdx.x;
    int j = idx >> 11;
    int c = idx & (KSEL - 1);
    Bb[(size_t)j * KSEL + c] = Ab[(size_t)j * NN + perm[c]];
}

#define BM 64
#define BN 64
#define BK 16

// ---------- GEMM1: A2rows = A[perm,:] * A   (2048 x 4096, bf16 out, exact ints) ----------
__global__ __launch_bounds__(256) void gemm_perm_rows(const bf16* __restrict__ Ab,
                                                      const int* __restrict__ perm,
                                                      bf16* __restrict__ A2b) {
    __shared__ float As[BK][BM + 4];
    __shared__ float Bs[BK][BN + 4];
    int tid = threadIdx.x;
    int tx = tid & 15, ty = tid >> 4;
    int row0 = blockIdx.y * BM, col0 = blockIdx.x * BN;
    float acc[4][4] = {};
    for (int k0 = 0; k0 < NN; k0 += BK) {
        #pragma unroll
        for (int t = tid; t < BM * BK; t += 256) {
            int m = t >> 4, kk = t & 15;
            int grow = perm[row0 + m];
            As[kk][m] = __bfloat162float(Ab[(size_t)grow * NN + k0 + kk]);
        }
        #pragma unroll
        for (int t = tid; t < BK * BN; t += 256) {
            int kk = t >> 6, n = t & 63;
            Bs[kk][n] = __bfloat162float(Ab[(size_t)(k0 + kk) * NN + col0 + n]);
        }
        __syncthreads();
        #pragma unroll
        for (int kk = 0; kk < BK; kk++) {
            float a[4], b[4];
            #pragma unroll
            for (int i = 0; i < 4; i++) a[i] = As[kk][ty * 4 + i];
            #pragma unroll
            for (int j = 0; j < 4; j++) b[j] = Bs[kk][tx * 4 + j];
            #pragma unroll
            for (int i = 0; i < 4; i++)
                #pragma unroll
                for (int j = 0; j < 4; j++)
                    acc[i][j] += a[i] * b[j];
        }
        __syncthreads();
    }
    #pragma unroll
    for (int i = 0; i < 4; i++) {
        int r = row0 + ty * 4 + i;
        #pragma unroll
        for (int j = 0; j < 4; j++) {
            int c = col0 + tx * 4 + j;
            A2b[(size_t)r * NN + c] = __float2bfloat16(acc[i][j]);
        }
    }
}

// ---------- GEMM2: A3pool = A2rows * B; epilogue fuses M_pool ----------
__global__ __launch_bounds__(256) void gemm_final(const bf16* __restrict__ A2b,
                                                  const bf16* __restrict__ Bb,
                                                  const bf16* __restrict__ Ab,
                                                  const int* __restrict__ perm,
                                                  const float* __restrict__ fw,
                                                  float* __restrict__ Mpool) {
    __shared__ float As[BK][BM + 4];
    __shared__ float Bs[BK][BN + 4];
    int tid = threadIdx.x;
    int tx = tid & 15, ty = tid >> 4;
    int row0 = blockIdx.y * BM, col0 = blockIdx.x * BN;
    float acc[4][4] = {};
    for (int k0 = 0; k0 < NN; k0 += BK) {
        #pragma unroll
        for (int t = tid; t < BM * BK; t += 256) {
            int m = t >> 4, kk = t & 15;
            As[kk][m] = __bfloat162float(A2b[(size_t)(row0 + m) * NN + k0 + kk]);
        }
        #pragma unroll
        for (int t = tid; t < BK * BN; t += 256) {
            int kk = t >> 6, n = t & 63;
            Bs[kk][n] = __bfloat162float(Bb[(size_t)(k0 + kk) * KSEL + col0 + n]);
        }
        __syncthreads();
        #pragma unroll
        for (int kk = 0; kk < BK; kk++) {
            float a[4], b[4];
            #pragma unroll
            for (int i = 0; i < 4; i++) a[i] = As[kk][ty * 4 + i];
            #pragma unroll
            for (int j = 0; j < 4; j++) b[j] = Bs[kk][tx * 4 + j];
            #pragma unroll
            for (int i = 0; i < 4; i++)
                #pragma unroll
                for (int j = 0; j < 4; j++)
                    acc[i][j] += a[i] * b[j];
        }
        __syncthreads();
    }
    float w0 = fw[0], w1 = fw[1], w2 = fw[2], w3 = fw[3];
    #pragma unroll
    for (int i = 0; i < 4; i++) {
        int r = row0 + ty * 4 + i;
        int pr = perm[r];
        #pragma unroll
        for (int j = 0; j < 4; j++) {
            int c = col0 + tx * 4 + j;
            int pc = perm[c];
            float m = w1 * __bfloat162float(Ab[(size_t)pr * NN + pc])
                    + w2 * __bfloat162float(A2b[(size_t)r * NN + pc])
                    + w3 * acc[i][j];
            if (r == c) m += w0;
            Mpool[(size_t)r * KSEL + c] = m;
        }
    }
}

// ---------- x_out = x[perm] * score[perm] ----------
__global__ void xout_kernel(const float* __restrict__ x, const int* __restrict__ perm,
                            const float* __restrict__ score_perm, float* __restrict__ out) {
    int idx = blockIdx.x * blockDim.x + threadIdx.x;
    int r = idx >> 8;
    out[idx] = x[(size_t)perm[r] * CH + (idx & 255)] * score_perm[r];
}

extern "C" void kernel_launch(void* const* d_in, const int* in_sizes, int n_in,
                              void* d_out, int out_size, void* d_ws, size_t ws_size,
                              hipStream_t stream) {
    const float* x  = (const float*)d_in[0];
    const int*   ei = (const int*)d_in[1];
    const float* tr = (const float*)d_in[2];
    const float* fw = (const float*)d_in[3];
    const float* pw = (const float*)d_in[4];

    float* out       = (float*)d_out;
    float* out_x     = out;                            // 2048*256
    float* out_M     = out + (size_t)KSEL * CH;        // 2048*2048
    float* out_perm  = out_M + (size_t)KSEL * KSEL;    // 2048
    float* out_score = out_perm + KSEL;                // 2048

    char* ws = (char*)d_ws;
    bf16*  Ab  = (bf16*)ws;                      // [0, 32Mi)   A bf16
    float* Af  = (float*)(ws + 33554432);        // [32Mi, 96Mi) A f32 (dead after convert)
    bf16*  Bb  = (bf16*)(ws + 33554432);         // [32Mi, 48Mi) A[:,perm] (reuses Af)
    bf16*  A2b = (bf16*)(ws + 50331648);         // [48Mi, 64Mi) A2[perm,:] (reuses Af)
    float* vec = (float*)(ws + 100663296);
    float* d1 = vec;
    float* d2 = vec + 4096;
    float* d3 = vec + 8192;
    float* score = vec + 12288;
    int*   perm = (int*)(vec + 16384);
    float* score_perm = vec + 18432;

    hipMemsetAsync(Af, 0, (size_t)NN * NN * 4, stream);
    hipMemsetAsync(vec, 0, 81920, stream);

    build_A<<<NE / 256, 256, 0, stream>>>(ei, Af, d1);
    convert_A<<<(NN * NN / 4) / 256, 256, 0, stream>>>(Af, Ab);
    spmv_edge<<<NE / 256, 256, 0, stream>>>(ei, d1, d2);   // d2 = rowsum(A^2)
    spmv_edge<<<NE / 256, 256, 0, stream>>>(ei, d2, d3);   // d3 = rowsum(A^3)
    score_kernel<<<(NN * 64) / 256, 256, 0, stream>>>(x, tr, d1, d2, d3, fw, pw, score);
    rank_kernel<<<NN / 256, 256, 0, stream>>>(score, perm, score_perm, out_perm, out_score);
    gather_cols<<<(NN * KSEL) / 256, 256, 0, stream>>>(Ab, perm, Bb);
    gemm_perm_rows<<<dim3(NN / BN, KSEL / BM), 256, 0, stream>>>(Ab, perm, A2b);
    gemm_final<<<dim3(KSEL / BN, KSEL / BM), 256, 0, stream>>>(A2b, Bb, Ab, perm, fw, out_M);
    xout_kernel<<<(KSEL * CH) / 256, 256, 0, stream>>>(x, perm, score_perm, out_x);
}

// Round 2
// 395.040 us; speedup vs baseline: 4.9310x; 4.9310x over previous
//
#include <hip/hip_runtime.h>
#include <hip/hip_bf16.h>

#define NN 4096
#define NE 131072
#define CH 256
#define KSEL 2048

typedef __hip_bfloat16 bf16;
typedef short bf16x8 __attribute__((ext_vector_type(8)));
typedef float f32x4 __attribute__((ext_vector_type(4)));

#define GLOAD_LDS16(g, l)                                                          \
    __builtin_amdgcn_global_load_lds((const __attribute__((address_space(1))) void*)(g), \
                                     (__attribute__((address_space(3))) void*)(l), 16, 0, 0)

// ---------- build A as packed u8 counts + row degree d1 ----------
__global__ void build_A(const int* __restrict__ ei, unsigned int* __restrict__ A32,
                        float* __restrict__ d1) {
    int e = blockIdx.x * blockDim.x + threadIdx.x;
    if (e < NE) {
        int r = ei[e];
        int c = ei[NE + e];
        size_t idx = (size_t)r * NN + c;
        atomicAdd(&A32[idx >> 2], 1u << ((idx & 3) * 8));
        atomicAdd(&d1[r], 1.0f);
    }
}

// ---------- u8 -> bf16 row-major Ab AND transposed Atb (tiled) ----------
__global__ __launch_bounds__(256) void convert_kernel(const unsigned char* __restrict__ A8,
                                                      bf16* __restrict__ Ab,
                                                      bf16* __restrict__ Atb) {
    __shared__ unsigned char tile[64][68];
    int t = threadIdx.x;
    int r = t >> 2, c16 = (t & 3) * 16;
    int gr = blockIdx.y * 64 + r;
    int gc = blockIdx.x * 64 + c16;
    union { uint4 q; unsigned char b[16]; } v;
    v.q = *(const uint4*)(A8 + (size_t)gr * NN + gc);
    bf16 ob[16];
    #pragma unroll
    for (int i = 0; i < 16; i++) ob[i] = __float2bfloat16((float)v.b[i]);
    bf16* dr = Ab + (size_t)gr * NN + gc;
    *(uint4*)dr = ((uint4*)ob)[0];
    *(uint4*)(dr + 8) = ((uint4*)ob)[1];
    #pragma unroll
    for (int i = 0; i < 16; i++) tile[r][c16 + i] = v.b[i];
    __syncthreads();
    int tr = t >> 2;          // original col -> output row
    int rr = (t & 3) * 16;    // original row offset -> output col
    bf16 ot[16];
    #pragma unroll
    for (int i = 0; i < 16; i++) ot[i] = __float2bfloat16((float)tile[rr + i][tr]);
    bf16* dt = Atb + (size_t)(blockIdx.x * 64 + tr) * NN + blockIdx.y * 64 + rr;
    *(uint4*)dt = ((uint4*)ot)[0];
    *(uint4*)(dt + 8) = ((uint4*)ot)[1];
}

// ---------- sparse matvec via edge list: vout[row] += vin[col] ----------
__global__ void spmv_edge(const int* __restrict__ ei, const float* __restrict__ vin,
                          float* __restrict__ vout) {
    int e = blockIdx.x * blockDim.x + threadIdx.x;
    if (e < NE) atomicAdd(&vout[ei[e]], vin[ei[NE + e]]);
}

// ---------- score = tanh(pw0 * (x . transform) + pw1 * degree) ----------
__global__ void score_kernel(const float* __restrict__ x, const float* __restrict__ tr,
                             const float* __restrict__ d1, const float* __restrict__ d2,
                             const float* __restrict__ d3, const float* __restrict__ fw,
                             const float* __restrict__ pw, float* __restrict__ score) {
    int gtid = blockIdx.x * blockDim.x + threadIdx.x;
    int node = gtid >> 6;
    int lane = gtid & 63;
    if (node >= NN) return;
    const float* xr = x + (size_t)node * CH;
    float s = 0.f;
    #pragma unroll
    for (int q = 0; q < CH; q += 64) s += xr[q + lane] * tr[q + lane];
    #pragma unroll
    for (int off = 32; off > 0; off >>= 1) s += __shfl_down(s, off);
    if (lane == 0) {
        float deg = fw[0] + fw[1] * d1[node] + fw[2] * d2[node] + fw[3] * d3[node];
        score[node] = tanhf(pw[0] * s + pw[1] * deg);
    }
}

// ---------- stable descending argsort via O(N^2) rank; top-KSEL ----------
__global__ void rank_kernel(const float* __restrict__ score, int* __restrict__ perm,
                            float* __restrict__ score_perm, float* __restrict__ out_perm,
                            float* __restrict__ out_score) {
    int i = blockIdx.x * blockDim.x + threadIdx.x;
    if (i >= NN) return;
    float si = score[i];
    int r = 0;
    for (int j = 0; j < NN; j++) {
        float sj = score[j];
        r += (int)((sj > si) | ((sj == si) & (j < i)));
    }
    if (r < KSEL) {
        perm[r] = i;
        score_perm[r] = si;
        out_perm[r] = (float)i;
        out_score[r] = si;
    }
}

// ---------- Bt2 = Atb[perm, :]  (== (A[:,perm])^T, 2048 x 4096 bf16) ----------
__global__ void bt2_gather(const bf16* __restrict__ Atb, const int* __restrict__ perm,
                           bf16* __restrict__ Bt2) {
    int idx = blockIdx.x * blockDim.x + threadIdx.x;
    int r = idx >> 9;
    int off = (idx & 511) * 8;
    *(uint4*)(Bt2 + (size_t)r * NN + off) =
        *(const uint4*)(Atb + (size_t)perm[r] * NN + off);
}

// ================= MFMA GEMMs: 128x128 tile, 4 waves, BK=32 =================
// GEMM1: A2[r,:] = A[perm[r],:] * A   (M=2048, N=4096, K=4096), bf16 out (exact ints)
__global__ __launch_bounds__(256) void gemm1_mfma(const bf16* __restrict__ Ab,
                                                  const bf16* __restrict__ Atb,
                                                  const int* __restrict__ perm,
                                                  bf16* __restrict__ A2b) {
    __shared__ bf16 As[128 * 32];
    __shared__ bf16 Bs[128 * 32];
    int tid = threadIdx.x;
    int wave = tid >> 6;
    int ln = tid & 15;
    int kq = (tid >> 4) & 3;
    int wr = wave >> 1, wc = wave & 1;
    int row0 = blockIdx.y * 128, col0 = blockIdx.x * 128;

    int srow = tid >> 2;
    int sk = (tid & 3) * 8;
    int ga0 = perm[row0 + srow];
    int ga1 = perm[row0 + 64 + srow];
    const bf16* agp0 = Ab + (size_t)ga0 * NN + sk;
    const bf16* agp1 = Ab + (size_t)ga1 * NN + sk;
    const bf16* bgp0 = Atb + (size_t)(col0 + srow) * NN + sk;
    const bf16* bgp1 = Atb + (size_t)(col0 + 64 + srow) * NN + sk;
    bf16* asl0 = As + wave * 512;
    bf16* asl1 = As + 2048 + wave * 512;
    bf16* bsl0 = Bs + wave * 512;
    bf16* bsl1 = Bs + 2048 + wave * 512;

    f32x4 acc[4][4] = {};
    for (int k0 = 0; k0 < NN; k0 += 32) {
        GLOAD_LDS16(agp0 + k0, asl0);
        GLOAD_LDS16(agp1 + k0, asl1);
        GLOAD_LDS16(bgp0 + k0, bsl0);
        GLOAD_LDS16(bgp1 + k0, bsl1);
        __syncthreads();
        bf16x8 a[4], b[4];
        #pragma unroll
        for (int m = 0; m < 4; m++)
            a[m] = *(const bf16x8*)(As + (wr * 64 + m * 16 + ln) * 32 + kq * 8);
        #pragma unroll
        for (int n = 0; n < 4; n++)
            b[n] = *(const bf16x8*)(Bs + (wc * 64 + n * 16 + ln) * 32 + kq * 8);
        #pragma unroll
        for (int m = 0; m < 4; m++)
            #pragma unroll
            for (int n = 0; n < 4; n++)
                acc[m][n] = __builtin_amdgcn_mfma_f32_16x16x32_bf16(a[m], b[n], acc[m][n], 0, 0, 0);
        __syncthreads();
    }
    #pragma unroll
    for (int m = 0; m < 4; m++) {
        #pragma unroll
        for (int n = 0; n < 4; n++) {
            int c = col0 + wc * 64 + n * 16 + ln;
            #pragma unroll
            for (int j = 0; j < 4; j++) {
                int r = row0 + wr * 64 + m * 16 + kq * 4 + j;
                A2b[(size_t)r * NN + c] = __float2bfloat16(acc[m][n][j]);
            }
        }
    }
}

// GEMM2: A3pp = A2 * Bt2^T (M=2048,N=2048,K=4096); epilogue fuses full M_pool
__global__ __launch_bounds__(256) void gemm2_mfma(const bf16* __restrict__ A2b,
                                                  const bf16* __restrict__ Bt2,
                                                  const int* __restrict__ perm,
                                                  const float* __restrict__ fw,
                                                  float* __restrict__ Mpool) {
    __shared__ bf16 As[128 * 32];
    __shared__ bf16 Bs[128 * 32];
    int tid = threadIdx.x;
    int wave = tid >> 6;
    int ln = tid & 15;
    int kq = (tid >> 4) & 3;
    int wr = wave >> 1, wc = wave & 1;
    int row0 = blockIdx.y * 128, col0 = blockIdx.x * 128;

    int srow = tid >> 2;
    int sk = (tid & 3) * 8;
    const bf16* agp0 = A2b + (size_t)(row0 + srow) * NN + sk;
    const bf16* agp1 = A2b + (size_t)(row0 + 64 + srow) * NN + sk;
    const bf16* bgp0 = Bt2 + (size_t)(col0 + srow) * NN + sk;
    const bf16* bgp1 = Bt2 + (size_t)(col0 + 64 + srow) * NN + sk;
    bf16* asl0 = As + wave * 512;
    bf16* asl1 = As + 2048 + wave * 512;
    bf16* bsl0 = Bs + wave * 512;
    bf16* bsl1 = Bs + 2048 + wave * 512;

    f32x4 acc[4][4] = {};
    for (int k0 = 0; k0 < NN; k0 += 32) {
        GLOAD_LDS16(agp0 + k0, asl0);
        GLOAD_LDS16(agp1 + k0, asl1);
        GLOAD_LDS16(bgp0 + k0, bsl0);
        GLOAD_LDS16(bgp1 + k0, bsl1);
        __syncthreads();
        bf16x8 a[4], b[4];
        #pragma unroll
        for (int m = 0; m < 4; m++)
            a[m] = *(const bf16x8*)(As + (wr * 64 + m * 16 + ln) * 32 + kq * 8);
        #pragma unroll
        for (int n = 0; n < 4; n++)
            b[n] = *(const bf16x8*)(Bs + (wc * 64 + n * 16 + ln) * 32 + kq * 8);
        #pragma unroll
        for (int m = 0; m < 4; m++)
            #pragma unroll
            for (int n = 0; n < 4; n++)
                acc[m][n] = __builtin_amdgcn_mfma_f32_16x16x32_bf16(a[m], b[n], acc[m][n], 0, 0, 0);
        __syncthreads();
    }
    float w0 = fw[0], w1 = fw[1], w2 = fw[2], w3 = fw[3];
    #pragma unroll
    for (int m = 0; m < 4; m++) {
        #pragma unroll
        for (int n = 0; n < 4; n++) {
            int c = col0 + wc * 64 + n * 16 + ln;
            int pc = perm[c];
            #pragma unroll
            for (int j = 0; j < 4; j++) {
                int r = row0 + wr * 64 + m * 16 + kq * 4 + j;
                int pr = perm[r];
                float app = __bfloat162float(Bt2[(size_t)c * NN + pr]);
                float a2p = __bfloat162float(A2b[(size_t)r * NN + pc]);
                float mv = w1 * app + w2 * a2p + w3 * acc[m][n][j];
                if (r == c) mv += w0;
                Mpool[(size_t)r * KSEL + c] = mv;
            }
        }
    }
}

// ---------- x_out = x[perm] * score[perm] ----------
__global__ void xout_kernel(const float* __restrict__ x, const int* __restrict__ perm,
                            const float* __restrict__ score_perm, float* __restrict__ out) {
    int idx = blockIdx.x * blockDim.x + threadIdx.x;
    int r = idx >> 8;
    out[idx] = x[(size_t)perm[r] * CH + (idx & 255)] * score_perm[r];
}

extern "C" void kernel_launch(void* const* d_in, const int* in_sizes, int n_in,
                              void* d_out, int out_size, void* d_ws, size_t ws_size,
                              hipStream_t stream) {
    const float* x  = (const float*)d_in[0];
    const int*   ei = (const int*)d_in[1];
    const float* tr = (const float*)d_in[2];
    const float* fw = (const float*)d_in[3];
    const float* pw = (const float*)d_in[4];

    float* out       = (float*)d_out;
    float* out_x     = out;                            // 2048*256
    float* out_M     = out + (size_t)KSEL * CH;        // 2048*2048
    float* out_perm  = out_M + (size_t)KSEL * KSEL;    // 2048
    float* out_score = out_perm + KSEL;                // 2048

    char* ws = (char*)d_ws;
    unsigned char* A8  = (unsigned char*)ws;           // [0,16Mi)  u8 counts (dead after convert)
    unsigned int*  A32 = (unsigned int*)ws;
    bf16* Bt2 = (bf16*)ws;                             // [0,16Mi)  reuses A8 after convert
    bf16* Ab  = (bf16*)(ws + 16777216);                // [16Mi,48Mi)
    bf16* Atb = (bf16*)(ws + 50331648);                // [48Mi,80Mi)
    bf16* A2b = (bf16*)(ws + 83886080);                // [80Mi,96Mi)
    float* vec = (float*)(ws + 100663296);             // [96Mi, +80KiB)
    float* d1 = vec;
    float* d2 = vec + 4096;
    float* d3 = vec + 8192;
    float* score = vec + 12288;
    int*   perm = (int*)(vec + 16384);
    float* score_perm = vec + 18432;

    hipMemsetAsync(A32, 0, (size_t)NN * NN, stream);
    hipMemsetAsync(vec, 0, 81920, stream);

    build_A<<<NE / 256, 256, 0, stream>>>(ei, A32, d1);
    spmv_edge<<<NE / 256, 256, 0, stream>>>(ei, d1, d2);   // d2 = rowsum(A^2)
    spmv_edge<<<NE / 256, 256, 0, stream>>>(ei, d2, d3);   // d3 = rowsum(A^3)
    score_kernel<<<(NN * 64) / 256, 256, 0, stream>>>(x, tr, d1, d2, d3, fw, pw, score);
    rank_kernel<<<NN / 256, 256, 0, stream>>>(score, perm, score_perm, out_perm, out_score);
    convert_kernel<<<dim3(64, 64), 256, 0, stream>>>(A8, Ab, Atb);
    bt2_gather<<<(KSEL * 512) / 256, 256, 0, stream>>>(Atb, perm, Bt2);
    gemm1_mfma<<<dim3(NN / 128, KSEL / 128), 256, 0, stream>>>(Ab, Atb, perm, A2b);
    gemm2_mfma<<<dim3(KSEL / 128, KSEL / 128), 256, 0, stream>>>(A2b, Bt2, perm, fw, out_M);
    xout_kernel<<<(KSEL * CH) / 256, 256, 0, stream>>>(x, perm, score_perm, out_x);
}

// Round 3
// 258.818 us; speedup vs baseline: 7.5263x; 1.5263x over previous
//
#include <hip/hip_runtime.h>
#include <hip/hip_bf16.h>

#define NN 4096
#define NE 131072
#define CH 256
#define KSEL 2048

typedef __hip_bfloat16 bf16;
typedef short bf16x8 __attribute__((ext_vector_type(8)));
typedef float f32x4 __attribute__((ext_vector_type(4)));

#define GLOAD_LDS16(g, l)                                                          \
    __builtin_amdgcn_global_load_lds((const __attribute__((address_space(1))) void*)(g), \
                                     (__attribute__((address_space(3))) void*)(l), 16, 0, 0)

// ---------- build A as packed u8 counts + row degree d1 ----------
__global__ void build_A(const int* __restrict__ ei, unsigned int* __restrict__ A32,
                        float* __restrict__ d1) {
    int e = blockIdx.x * blockDim.x + threadIdx.x;
    if (e < NE) {
        int r = ei[e];
        int c = ei[NE + e];
        size_t idx = (size_t)r * NN + c;
        atomicAdd(&A32[idx >> 2], 1u << ((idx & 3) * 8));
        atomicAdd(&d1[r], 1.0f);
    }
}

// ---------- u8 -> bf16 row-major Ab AND transposed Atb (tiled) ----------
__global__ __launch_bounds__(256) void convert_kernel(const unsigned char* __restrict__ A8,
                                                      bf16* __restrict__ Ab,
                                                      bf16* __restrict__ Atb) {
    __shared__ unsigned char tile[64][68];
    int t = threadIdx.x;
    int r = t >> 2, c16 = (t & 3) * 16;
    int gr = blockIdx.y * 64 + r;
    int gc = blockIdx.x * 64 + c16;
    union { uint4 q; unsigned char b[16]; } v;
    v.q = *(const uint4*)(A8 + (size_t)gr * NN + gc);
    bf16 ob[16];
    #pragma unroll
    for (int i = 0; i < 16; i++) ob[i] = __float2bfloat16((float)v.b[i]);
    bf16* dr = Ab + (size_t)gr * NN + gc;
    *(uint4*)dr = ((uint4*)ob)[0];
    *(uint4*)(dr + 8) = ((uint4*)ob)[1];
    #pragma unroll
    for (int i = 0; i < 16; i++) tile[r][c16 + i] = v.b[i];
    __syncthreads();
    int tr = t >> 2;          // original col -> output row
    int rr = (t & 3) * 16;    // original row offset -> output col
    bf16 ot[16];
    #pragma unroll
    for (int i = 0; i < 16; i++) ot[i] = __float2bfloat16((float)tile[rr + i][tr]);
    bf16* dt = Atb + (size_t)(blockIdx.x * 64 + tr) * NN + blockIdx.y * 64 + rr;
    *(uint4*)dt = ((uint4*)ot)[0];
    *(uint4*)(dt + 8) = ((uint4*)ot)[1];
}

// ---------- sparse matvec via edge list: vout[row] += vin[col] ----------
__global__ void spmv_edge(const int* __restrict__ ei, const float* __restrict__ vin,
                          float* __restrict__ vout) {
    int e = blockIdx.x * blockDim.x + threadIdx.x;
    if (e < NE) atomicAdd(&vout[ei[e]], vin[ei[NE + e]]);
}

// ---------- score = tanh(pw0 * (x . transform) + pw1 * degree) ----------
__global__ void score_kernel(const float* __restrict__ x, const float* __restrict__ tr,
                             const float* __restrict__ d1, const float* __restrict__ d2,
                             const float* __restrict__ d3, const float* __restrict__ fw,
                             const float* __restrict__ pw, float* __restrict__ score) {
    int gtid = blockIdx.x * blockDim.x + threadIdx.x;
    int node = gtid >> 6;
    int lane = gtid & 63;
    if (node >= NN) return;
    const float* xr = x + (size_t)node * CH;
    float s = 0.f;
    #pragma unroll
    for (int q = 0; q < CH; q += 64) s += xr[q + lane] * tr[q + lane];
    #pragma unroll
    for (int off = 32; off > 0; off >>= 1) s += __shfl_down(s, off);
    if (lane == 0) {
        float deg = fw[0] + fw[1] * d1[node] + fw[2] * d2[node] + fw[3] * d3[node];
        score[node] = tanhf(pw[0] * s + pw[1] * deg);
    }
}

// ---------- stable descending argsort: one block per node i ----------
// rank[i] = #{j : s[j] > s[i]} + #{j < i : s[j] == s[i]}  (== jnp stable argsort(-s))
__global__ __launch_bounds__(256) void rank_kernel(const float* __restrict__ score,
                                                   int* __restrict__ perm,
                                                   float* __restrict__ score_perm,
                                                   float* __restrict__ out_perm,
                                                   float* __restrict__ out_score) {
    __shared__ int wsum[4];
    int i = blockIdx.x;
    int t = threadIdx.x;
    float si = score[i];
    int cnt = 0;
    #pragma unroll
    for (int it = 0; it < NN / 4 / 256; it++) {
        int j4 = it * 256 + t;
        float4 s4 = reinterpret_cast<const float4*>(score)[j4];
        int j = j4 * 4;
        cnt += (int)((s4.x > si) | ((s4.x == si) & (j + 0 < i)));
        cnt += (int)((s4.y > si) | ((s4.y == si) & (j + 1 < i)));
        cnt += (int)((s4.z > si) | ((s4.z == si) & (j + 2 < i)));
        cnt += (int)((s4.w > si) | ((s4.w == si) & (j + 3 < i)));
    }
    #pragma unroll
    for (int off = 32; off > 0; off >>= 1) cnt += __shfl_down(cnt, off);
    if ((t & 63) == 0) wsum[t >> 6] = cnt;
    __syncthreads();
    if (t == 0) {
        int r = wsum[0] + wsum[1] + wsum[2] + wsum[3];
        if (r < KSEL) {
            perm[r] = i;
            score_perm[r] = si;
            out_perm[r] = (float)i;
            out_score[r] = si;
        }
    }
}

// ---------- Bt2 = Atb[perm, :]  (== (A[:,perm])^T, 2048 x 4096 bf16) ----------
__global__ void bt2_gather(const bf16* __restrict__ Atb, const int* __restrict__ perm,
                           bf16* __restrict__ Bt2) {
    int idx = blockIdx.x * blockDim.x + threadIdx.x;
    int r = idx >> 9;
    int off = (idx & 511) * 8;
    *(uint4*)(Bt2 + (size_t)r * NN + off) =
        *(const uint4*)(Atb + (size_t)perm[r] * NN + off);
}

// ================= MFMA GEMMs: 128x128 tile, 4 waves, BK=32 =================
// GEMM1: A2[r,:] = A[perm[r],:] * A   (M=2048, N=4096, K=4096), bf16 out (exact ints)
__global__ __launch_bounds__(256) void gemm1_mfma(const bf16* __restrict__ Ab,
                                                  const bf16* __restrict__ Atb,
                                                  const int* __restrict__ perm,
                                                  bf16* __restrict__ A2b) {
    __shared__ bf16 As[128 * 32];
    __shared__ bf16 Bs[128 * 32];
    int tid = threadIdx.x;
    int wave = tid >> 6;
    int ln = tid & 15;
    int kq = (tid >> 4) & 3;
    int wr = wave >> 1, wc = wave & 1;
    int row0 = blockIdx.y * 128, col0 = blockIdx.x * 128;

    int srow = tid >> 2;
    int sk = (tid & 3) * 8;
    int ga0 = perm[row0 + srow];
    int ga1 = perm[row0 + 64 + srow];
    const bf16* agp0 = Ab + (size_t)ga0 * NN + sk;
    const bf16* agp1 = Ab + (size_t)ga1 * NN + sk;
    const bf16* bgp0 = Atb + (size_t)(col0 + srow) * NN + sk;
    const bf16* bgp1 = Atb + (size_t)(col0 + 64 + srow) * NN + sk;
    bf16* asl0 = As + wave * 512;
    bf16* asl1 = As + 2048 + wave * 512;
    bf16* bsl0 = Bs + wave * 512;
    bf16* bsl1 = Bs + 2048 + wave * 512;

    f32x4 acc[4][4] = {};
    for (int k0 = 0; k0 < NN; k0 += 32) {
        GLOAD_LDS16(agp0 + k0, asl0);
        GLOAD_LDS16(agp1 + k0, asl1);
        GLOAD_LDS16(bgp0 + k0, bsl0);
        GLOAD_LDS16(bgp1 + k0, bsl1);
        __syncthreads();
        bf16x8 a[4], b[4];
        #pragma unroll
        for (int m = 0; m < 4; m++)
            a[m] = *(const bf16x8*)(As + (wr * 64 + m * 16 + ln) * 32 + kq * 8);
        #pragma unroll
        for (int n = 0; n < 4; n++)
            b[n] = *(const bf16x8*)(Bs + (wc * 64 + n * 16 + ln) * 32 + kq * 8);
        #pragma unroll
        for (int m = 0; m < 4; m++)
            #pragma unroll
            for (int n = 0; n < 4; n++)
                acc[m][n] = __builtin_amdgcn_mfma_f32_16x16x32_bf16(a[m], b[n], acc[m][n], 0, 0, 0);
        __syncthreads();
    }
    #pragma unroll
    for (int m = 0; m < 4; m++) {
        #pragma unroll
        for (int n = 0; n < 4; n++) {
            int c = col0 + wc * 64 + n * 16 + ln;
            #pragma unroll
            for (int j = 0; j < 4; j++) {
                int r = row0 + wr * 64 + m * 16 + kq * 4 + j;
                A2b[(size_t)r * NN + c] = __float2bfloat16(acc[m][n][j]);
            }
        }
    }
}

// GEMM2: A3pp = A2 * Bt2^T (M=2048,N=2048,K=4096); epilogue fuses full M_pool
__global__ __launch_bounds__(256) void gemm2_mfma(const bf16* __restrict__ A2b,
                                                  const bf16* __restrict__ Bt2,
                                                  const int* __restrict__ perm,
                                                  const float* __restrict__ fw,
                                                  float* __restrict__ Mpool) {
    __shared__ bf16 As[128 * 32];
    __shared__ bf16 Bs[128 * 32];
    int tid = threadIdx.x;
    int wave = tid >> 6;
    int ln = tid & 15;
    int kq = (tid >> 4) & 3;
    int wr = wave >> 1, wc = wave & 1;
    int row0 = blockIdx.y * 128, col0 = blockIdx.x * 128;

    int srow = tid >> 2;
    int sk = (tid & 3) * 8;
    const bf16* agp0 = A2b + (size_t)(row0 + srow) * NN + sk;
    const bf16* agp1 = A2b + (size_t)(row0 + 64 + srow) * NN + sk;
    const bf16* bgp0 = Bt2 + (size_t)(col0 + srow) * NN + sk;
    const bf16* bgp1 = Bt2 + (size_t)(col0 + 64 + srow) * NN + sk;
    bf16* asl0 = As + wave * 512;
    bf16* asl1 = As + 2048 + wave * 512;
    bf16* bsl0 = Bs + wave * 512;
    bf16* bsl1 = Bs + 2048 + wave * 512;

    f32x4 acc[4][4] = {};
    for (int k0 = 0; k0 < NN; k0 += 32) {
        GLOAD_LDS16(agp0 + k0, asl0);
        GLOAD_LDS16(agp1 + k0, asl1);
        GLOAD_LDS16(bgp0 + k0, bsl0);
        GLOAD_LDS16(bgp1 + k0, bsl1);
        __syncthreads();
        bf16x8 a[4], b[4];
        #pragma unroll
        for (int m = 0; m < 4; m++)
            a[m] = *(const bf16x8*)(As + (wr * 64 + m * 16 + ln) * 32 + kq * 8);
        #pragma unroll
        for (int n = 0; n < 4; n++)
            b[n] = *(const bf16x8*)(Bs + (wc * 64 + n * 16 + ln) * 32 + kq * 8);
        #pragma unroll
        for (int m = 0; m < 4; m++)
            #pragma unroll
            for (int n = 0; n < 4; n++)
                acc[m][n] = __builtin_amdgcn_mfma_f32_16x16x32_bf16(a[m], b[n], acc[m][n], 0, 0, 0);
        __syncthreads();
    }
    float w0 = fw[0], w1 = fw[1], w2 = fw[2], w3 = fw[3];
    #pragma unroll
    for (int m = 0; m < 4; m++) {
        #pragma unroll
        for (int n = 0; n < 4; n++) {
            int c = col0 + wc * 64 + n * 16 + ln;
            int pc = perm[c];
            #pragma unroll
            for (int j = 0; j < 4; j++) {
                int r = row0 + wr * 64 + m * 16 + kq * 4 + j;
                int pr = perm[r];
                float app = __bfloat162float(Bt2[(size_t)c * NN + pr]);
                float a2p = __bfloat162float(A2b[(size_t)r * NN + pc]);
                float mv = w1 * app + w2 * a2p + w3 * acc[m][n][j];
                if (r == c) mv += w0;
                Mpool[(size_t)r * KSEL + c] = mv;
            }
        }
    }
}

// ---------- x_out = x[perm] * score[perm] ----------
__global__ void xout_kernel(const float* __restrict__ x, const int* __restrict__ perm,
                            const float* __restrict__ score_perm, float* __restrict__ out) {
    int idx = blockIdx.x * blockDim.x + threadIdx.x;
    int r = idx >> 8;
    out[idx] = x[(size_t)perm[r] * CH + (idx & 255)] * score_perm[r];
}

extern "C" void kernel_launch(void* const* d_in, const int* in_sizes, int n_in,
                              void* d_out, int out_size, void* d_ws, size_t ws_size,
                              hipStream_t stream) {
    const float* x  = (const float*)d_in[0];
    const int*   ei = (const int*)d_in[1];
    const float* tr = (const float*)d_in[2];
    const float* fw = (const float*)d_in[3];
    const float* pw = (const float*)d_in[4];

    float* out       = (float*)d_out;
    float* out_x     = out;                            // 2048*256
    float* out_M     = out + (size_t)KSEL * CH;        // 2048*2048
    float* out_perm  = out_M + (size_t)KSEL * KSEL;    // 2048
    float* out_score = out_perm + KSEL;                // 2048

    char* ws = (char*)d_ws;
    unsigned char* A8  = (unsigned char*)ws;           // [0,16Mi)  u8 counts (dead after convert)
    unsigned int*  A32 = (unsigned int*)ws;
    bf16* Bt2 = (bf16*)ws;                             // [0,16Mi)  reuses A8 after convert
    bf16* Ab  = (bf16*)(ws + 16777216);                // [16Mi,48Mi)
    bf16* Atb = (bf16*)(ws + 50331648);                // [48Mi,80Mi)
    bf16* A2b = (bf16*)(ws + 83886080);                // [80Mi,96Mi)
    float* vec = (float*)(ws + 100663296);             // [96Mi, +80KiB)
    float* d1 = vec;
    float* d2 = vec + 4096;
    float* d3 = vec + 8192;
    float* score = vec + 12288;
    int*   perm = (int*)(vec + 16384);
    float* score_perm = vec + 18432;

    hipMemsetAsync(A32, 0, (size_t)NN * NN, stream);
    hipMemsetAsync(vec, 0, 81920, stream);

    build_A<<<NE / 256, 256, 0, stream>>>(ei, A32, d1);
    spmv_edge<<<NE / 256, 256, 0, stream>>>(ei, d1, d2);   // d2 = rowsum(A^2)
    spmv_edge<<<NE / 256, 256, 0, stream>>>(ei, d2, d3);   // d3 = rowsum(A^3)
    score_kernel<<<(NN * 64) / 256, 256, 0, stream>>>(x, tr, d1, d2, d3, fw, pw, score);
    rank_kernel<<<NN, 256, 0, stream>>>(score, perm, score_perm, out_perm, out_score);
    convert_kernel<<<dim3(64, 64), 256, 0, stream>>>(A8, Ab, Atb);
    bt2_gather<<<(KSEL * 512) / 256, 256, 0, stream>>>(Atb, perm, Bt2);
    gemm1_mfma<<<dim3(NN / 128, KSEL / 128), 256, 0, stream>>>(Ab, Atb, perm, A2b);
    gemm2_mfma<<<dim3(KSEL / 128, KSEL / 128), 256, 0, stream>>>(A2b, Bt2, perm, fw, out_M);
    xout_kernel<<<(KSEL * CH) / 256, 256, 0, stream>>>(x, perm, score_perm, out_x);
}

// Round 4
// 249.461 us; speedup vs baseline: 7.8086x; 1.0375x over previous
//
#include <hip/hip_runtime.h>
#include <hip/hip_bf16.h>

#define NN 4096
#define NE 131072
#define CH 256
#define KSEL 2048

typedef __hip_bfloat16 bf16;
typedef short bf16x8 __attribute__((ext_vector_type(8)));
typedef float f32x4 __attribute__((ext_vector_type(4)));

#define GLOAD_LDS16(g, l)                                                          \
    __builtin_amdgcn_global_load_lds((const __attribute__((address_space(1))) void*)(g), \
                                     (__attribute__((address_space(3))) void*)(l), 16, 0, 0)

__device__ __forceinline__ float bf2f(unsigned short u) {
    union { unsigned int i; float f; } v;
    v.i = ((unsigned int)u) << 16;
    return v.f;
}

// ---------- build A as packed u8 counts + row degree d1 ----------
__global__ void build_A(const int* __restrict__ ei, unsigned int* __restrict__ A32,
                        float* __restrict__ d1) {
    int e = blockIdx.x * blockDim.x + threadIdx.x;
    if (e < NE) {
        int r = ei[e];
        int c = ei[NE + e];
        size_t idx = (size_t)r * NN + c;
        atomicAdd(&A32[idx >> 2], 1u << ((idx & 3) * 8));
        atomicAdd(&d1[r], 1.0f);
    }
}

// ---------- u8 -> bf16 row-major Ab AND transposed Atb (tiled) ----------
__global__ __launch_bounds__(256) void convert_kernel(const unsigned char* __restrict__ A8,
                                                      bf16* __restrict__ Ab,
                                                      bf16* __restrict__ Atb) {
    __shared__ unsigned char tile[64][68];
    int t = threadIdx.x;
    int r = t >> 2, c16 = (t & 3) * 16;
    int gr = blockIdx.y * 64 + r;
    int gc = blockIdx.x * 64 + c16;
    union { uint4 q; unsigned char b[16]; } v;
    v.q = *(const uint4*)(A8 + (size_t)gr * NN + gc);
    bf16 ob[16];
    #pragma unroll
    for (int i = 0; i < 16; i++) ob[i] = __float2bfloat16((float)v.b[i]);
    bf16* dr = Ab + (size_t)gr * NN + gc;
    *(uint4*)dr = ((uint4*)ob)[0];
    *(uint4*)(dr + 8) = ((uint4*)ob)[1];
    #pragma unroll
    for (int i = 0; i < 16; i++) tile[r][c16 + i] = v.b[i];
    __syncthreads();
    int tr = t >> 2;
    int rr = (t & 3) * 16;
    bf16 ot[16];
    #pragma unroll
    for (int i = 0; i < 16; i++) ot[i] = __float2bfloat16((float)tile[rr + i][tr]);
    bf16* dt = Atb + (size_t)(blockIdx.x * 64 + tr) * NN + blockIdx.y * 64 + rr;
    *(uint4*)dt = ((uint4*)ot)[0];
    *(uint4*)(dt + 8) = ((uint4*)ot)[1];
}

// ---------- sparse matvec via edge list ----------
__global__ void spmv_edge(const int* __restrict__ ei, const float* __restrict__ vin,
                          float* __restrict__ vout) {
    int e = blockIdx.x * blockDim.x + threadIdx.x;
    if (e < NE) atomicAdd(&vout[ei[e]], vin[ei[NE + e]]);
}

// ---------- score = tanh(pw0 * (x . transform) + pw1 * degree) ----------
__global__ void score_kernel(const float* __restrict__ x, const float* __restrict__ tr,
                             const float* __restrict__ d1, const float* __restrict__ d2,
                             const float* __restrict__ d3, const float* __restrict__ fw,
                             const float* __restrict__ pw, float* __restrict__ score) {
    int gtid = blockIdx.x * blockDim.x + threadIdx.x;
    int node = gtid >> 6;
    int lane = gtid & 63;
    if (node >= NN) return;
    const float* xr = x + (size_t)node * CH;
    float s = 0.f;
    #pragma unroll
    for (int q = 0; q < CH; q += 64) s += xr[q + lane] * tr[q + lane];
    #pragma unroll
    for (int off = 32; off > 0; off >>= 1) s += __shfl_down(s, off);
    if (lane == 0) {
        float deg = fw[0] + fw[1] * d1[node] + fw[2] * d2[node] + fw[3] * d3[node];
        score[node] = tanhf(pw[0] * s + pw[1] * deg);
    }
}

// ---------- stable descending argsort: one block per node i ----------
__global__ __launch_bounds__(256) void rank_kernel(const float* __restrict__ score,
                                                   int* __restrict__ perm,
                                                   float* __restrict__ score_perm,
                                                   float* __restrict__ out_perm,
                                                   float* __restrict__ out_score) {
    __shared__ int wsum[4];
    int i = blockIdx.x;
    int t = threadIdx.x;
    float si = score[i];
    int cnt = 0;
    #pragma unroll
    for (int it = 0; it < NN / 4 / 256; it++) {
        int j4 = it * 256 + t;
        float4 s4 = reinterpret_cast<const float4*>(score)[j4];
        int j = j4 * 4;
        cnt += (int)((s4.x > si) | ((s4.x == si) & (j + 0 < i)));
        cnt += (int)((s4.y > si) | ((s4.y == si) & (j + 1 < i)));
        cnt += (int)((s4.z > si) | ((s4.z == si) & (j + 2 < i)));
        cnt += (int)((s4.w > si) | ((s4.w == si) & (j + 3 < i)));
    }
    #pragma unroll
    for (int off = 32; off > 0; off >>= 1) cnt += __shfl_down(cnt, off);
    if ((t & 63) == 0) wsum[t >> 6] = cnt;
    __syncthreads();
    if (t == 0) {
        int r = wsum[0] + wsum[1] + wsum[2] + wsum[3];
        if (r < KSEL) {
            perm[r] = i;
            score_perm[r] = si;
            out_perm[r] = (float)i;
            out_score[r] = si;
        }
    }
}

// ---------- Bt2 = Atb[perm, :]  (== (A[:,perm])^T, 2048 x 4096 bf16) ----------
__global__ void bt2_gather(const bf16* __restrict__ Atb, const int* __restrict__ perm,
                           bf16* __restrict__ Bt2) {
    int idx = blockIdx.x * blockDim.x + threadIdx.x;
    int r = idx >> 9;
    int off = (idx & 511) * 8;
    *(uint4*)(Bt2 + (size_t)r * NN + off) =
        *(const uint4*)(Atb + (size_t)perm[r] * NN + off);
}

// ================= GEMM1: A2[r,:] = A[perm[r],:] * A  (128x128 tile) =================
__global__ __launch_bounds__(256) void gemm1_mfma(const bf16* __restrict__ Ab,
                                                  const bf16* __restrict__ Atb,
                                                  const int* __restrict__ perm,
                                                  bf16* __restrict__ A2b) {
    __shared__ bf16 As[128 * 32];
    __shared__ bf16 Bs[128 * 32];
    int tid = threadIdx.x;
    int wave = tid >> 6;
    int ln = tid & 15;
    int kq = (tid >> 4) & 3;
    int wr = wave >> 1, wc = wave & 1;
    int row0 = blockIdx.y * 128, col0 = blockIdx.x * 128;

    int srow = tid >> 2;
    int sk = (tid & 3) * 8;
    int ga0 = perm[row0 + srow];
    int ga1 = perm[row0 + 64 + srow];
    const bf16* agp0 = Ab + (size_t)ga0 * NN + sk;
    const bf16* agp1 = Ab + (size_t)ga1 * NN + sk;
    const bf16* bgp0 = Atb + (size_t)(col0 + srow) * NN + sk;
    const bf16* bgp1 = Atb + (size_t)(col0 + 64 + srow) * NN + sk;
    bf16* asl0 = As + wave * 512;
    bf16* asl1 = As + 2048 + wave * 512;
    bf16* bsl0 = Bs + wave * 512;
    bf16* bsl1 = Bs + 2048 + wave * 512;

    f32x4 acc[4][4] = {};
    for (int k0 = 0; k0 < NN; k0 += 32) {
        GLOAD_LDS16(agp0 + k0, asl0);
        GLOAD_LDS16(agp1 + k0, asl1);
        GLOAD_LDS16(bgp0 + k0, bsl0);
        GLOAD_LDS16(bgp1 + k0, bsl1);
        __syncthreads();
        bf16x8 a[4], b[4];
        #pragma unroll
        for (int m = 0; m < 4; m++)
            a[m] = *(const bf16x8*)(As + (wr * 64 + m * 16 + ln) * 32 + kq * 8);
        #pragma unroll
        for (int n = 0; n < 4; n++)
            b[n] = *(const bf16x8*)(Bs + (wc * 64 + n * 16 + ln) * 32 + kq * 8);
        #pragma unroll
        for (int m = 0; m < 4; m++)
            #pragma unroll
            for (int n = 0; n < 4; n++)
                acc[m][n] = __builtin_amdgcn_mfma_f32_16x16x32_bf16(a[m], b[n], acc[m][n], 0, 0, 0);
        __syncthreads();
    }
    #pragma unroll
    for (int m = 0; m < 4; m++) {
        #pragma unroll
        for (int n = 0; n < 4; n++) {
            int c = col0 + wc * 64 + n * 16 + ln;
            #pragma unroll
            for (int j = 0; j < 4; j++) {
                int r = row0 + wr * 64 + m * 16 + kq * 4 + j;
                A2b[(size_t)r * NN + c] = __float2bfloat16(acc[m][n][j]);
            }
        }
    }
}

// ---------- G[r,:] = w3*A2[r,:] + w2*A[pr,:] + w1*e_pr  (in place over A2b) ----------
__global__ void fuse_G(const bf16* __restrict__ Ab, const int* __restrict__ perm,
                       const float* __restrict__ fw, bf16* __restrict__ A2b) {
    int idx = blockIdx.x * blockDim.x + threadIdx.x;
    int r = idx >> 9;
    int kt = (idx & 511) * 8;
    int pr = perm[r];
    float w1 = fw[1], w2 = fw[2], w3 = fw[3];
    union U { uint4 q; unsigned short s[8]; } ua, ub, uo;
    ua.q = *(const uint4*)(A2b + (size_t)r * NN + kt);
    ub.q = *(const uint4*)(Ab + (size_t)pr * NN + kt);
    #pragma unroll
    for (int i = 0; i < 8; i++) {
        float g = w3 * bf2f(ua.s[i]) + w2 * bf2f(ub.s[i]) + ((kt + i) == pr ? w1 : 0.f);
        bf16 h = __float2bfloat16(g);
        uo.s[i] = *reinterpret_cast<unsigned short*>(&h);
    }
    *(uint4*)(A2b + (size_t)r * NN + kt) = uo.q;
}

// ===== GEMM2: M_pool = G * Bt2^T + w0*I  (128x64 tile, clean epilogue) =====
__global__ __launch_bounds__(256) void gemm2_mfma(const bf16* __restrict__ Gb,
                                                  const bf16* __restrict__ Bt2,
                                                  const float* __restrict__ fw,
                                                  float* __restrict__ Mpool) {
    __shared__ bf16 As[128 * 32];
    __shared__ bf16 Bs[64 * 32];
    int tid = threadIdx.x;
    int wave = tid >> 6;
    int ln = tid & 15;
    int kq = (tid >> 4) & 3;
    int wr = wave >> 1, wc = wave & 1;
    int row0 = blockIdx.y * 128, col0 = blockIdx.x * 64;

    int srow = tid >> 2;
    int sk = (tid & 3) * 8;
    const bf16* agp0 = Gb + (size_t)(row0 + srow) * NN + sk;
    const bf16* agp1 = Gb + (size_t)(row0 + 64 + srow) * NN + sk;
    const bf16* bgp0 = Bt2 + (size_t)(col0 + srow) * NN + sk;
    bf16* asl0 = As + wave * 512;
    bf16* asl1 = As + 2048 + wave * 512;
    bf16* bsl0 = Bs + wave * 512;

    f32x4 acc[4][2] = {};
    for (int k0 = 0; k0 < NN; k0 += 32) {
        GLOAD_LDS16(agp0 + k0, asl0);
        GLOAD_LDS16(agp1 + k0, asl1);
        GLOAD_LDS16(bgp0 + k0, bsl0);
        __syncthreads();
        bf16x8 a[4], b[2];
        #pragma unroll
        for (int m = 0; m < 4; m++)
            a[m] = *(const bf16x8*)(As + (wr * 64 + m * 16 + ln) * 32 + kq * 8);
        #pragma unroll
        for (int n = 0; n < 2; n++)
            b[n] = *(const bf16x8*)(Bs + (wc * 32 + n * 16 + ln) * 32 + kq * 8);
        #pragma unroll
        for (int m = 0; m < 4; m++)
            #pragma unroll
            for (int n = 0; n < 2; n++)
                acc[m][n] = __builtin_amdgcn_mfma_f32_16x16x32_bf16(a[m], b[n], acc[m][n], 0, 0, 0);
        __syncthreads();
    }
    float w0 = fw[0];
    #pragma unroll
    for (int m = 0; m < 4; m++) {
        #pragma unroll
        for (int n = 0; n < 2; n++) {
            int c = col0 + wc * 32 + n * 16 + ln;
            #pragma unroll
            for (int j = 0; j < 4; j++) {
                int r = row0 + wr * 64 + m * 16 + kq * 4 + j;
                float mv = acc[m][n][j];
                if (r == c) mv += w0;
                Mpool[(size_t)r * KSEL + c] = mv;
            }
        }
    }
}

// ---------- x_out = x[perm] * score[perm] ----------
__global__ void xout_kernel(const float* __restrict__ x, const int* __restrict__ perm,
                            const float* __restrict__ score_perm, float* __restrict__ out) {
    int idx = blockIdx.x * blockDim.x + threadIdx.x;
    int r = idx >> 8;
    out[idx] = x[(size_t)perm[r] * CH + (idx & 255)] * score_perm[r];
}

extern "C" void kernel_launch(void* const* d_in, const int* in_sizes, int n_in,
                              void* d_out, int out_size, void* d_ws, size_t ws_size,
                              hipStream_t stream) {
    const float* x  = (const float*)d_in[0];
    const int*   ei = (const int*)d_in[1];
    const float* tr = (const float*)d_in[2];
    const float* fw = (const float*)d_in[3];
    const float* pw = (const float*)d_in[4];

    float* out       = (float*)d_out;
    float* out_x     = out;
    float* out_M     = out + (size_t)KSEL * CH;
    float* out_perm  = out_M + (size_t)KSEL * KSEL;
    float* out_score = out_perm + KSEL;

    char* ws = (char*)d_ws;
    unsigned char* A8  = (unsigned char*)ws;           // [0,16Mi)
    unsigned int*  A32 = (unsigned int*)ws;
    bf16* Bt2 = (bf16*)ws;                             // [0,16Mi) reuses A8 after convert
    bf16* Ab  = (bf16*)(ws + 16777216);                // [16Mi,48Mi)
    bf16* Atb = (bf16*)(ws + 50331648);                // [48Mi,80Mi)
    bf16* A2b = (bf16*)(ws + 83886080);                // [80Mi,96Mi)  (becomes G in place)
    float* vec = (float*)(ws + 100663296);
    float* d1 = vec;
    float* d2 = vec + 4096;
    float* d3 = vec + 8192;
    float* score = vec + 12288;
    int*   perm = (int*)(vec + 16384);
    float* score_perm = vec + 18432;

    hipMemsetAsync(A32, 0, (size_t)NN * NN, stream);
    hipMemsetAsync(vec, 0, 81920, stream);

    build_A<<<NE / 256, 256, 0, stream>>>(ei, A32, d1);
    spmv_edge<<<NE / 256, 256, 0, stream>>>(ei, d1, d2);
    spmv_edge<<<NE / 256, 256, 0, stream>>>(ei, d2, d3);
    score_kernel<<<(NN * 64) / 256, 256, 0, stream>>>(x, tr, d1, d2, d3, fw, pw, score);
    rank_kernel<<<NN, 256, 0, stream>>>(score, perm, score_perm, out_perm, out_score);
    convert_kernel<<<dim3(64, 64), 256, 0, stream>>>(A8, Ab, Atb);
    bt2_gather<<<(KSEL * 512) / 256, 256, 0, stream>>>(Atb, perm, Bt2);
    gemm1_mfma<<<dim3(NN / 128, KSEL / 128), 256, 0, stream>>>(Ab, Atb, perm, A2b);
    fuse_G<<<(KSEL * 512) / 256, 256, 0, stream>>>(Ab, perm, fw, A2b);
    gemm2_mfma<<<dim3(KSEL / 64, KSEL / 128), 256, 0, stream>>>(A2b, Bt2, fw, out_M);
    xout_kernel<<<(KSEL * CH) / 256, 256, 0, stream>>>(x, perm, score_perm, out_x);
}

// Round 5
// 205.760 us; speedup vs baseline: 9.4671x; 1.2124x over previous
//
#include <hip/hip_runtime.h>
#include <hip/hip_bf16.h>

#define NN 4096
#define NE 131072
#define CH 256
#define KSEL 2048

typedef __hip_bfloat16 bf16;
typedef short bf16x8 __attribute__((ext_vector_type(8)));
typedef float f32x4 __attribute__((ext_vector_type(4)));

#define GLOAD_LDS16(g, l)                                                          \
    __builtin_amdgcn_global_load_lds((const __attribute__((address_space(1))) void*)(g), \
                                     (__attribute__((address_space(3))) void*)(l), 16, 0, 0)

__device__ __forceinline__ float bf2f(unsigned short u) {
    union { unsigned int i; float f; } v;
    v.i = ((unsigned int)u) << 16;
    return v.f;
}

// ---------- build A as packed u8 counts + float degree d1 + int row counts ----------
__global__ void build_A(const int* __restrict__ ei, unsigned int* __restrict__ A32,
                        float* __restrict__ d1, int* __restrict__ rowcnt) {
    int e = blockIdx.x * blockDim.x + threadIdx.x;
    if (e < NE) {
        int r = ei[e];
        int c = ei[NE + e];
        size_t idx = (size_t)r * NN + c;
        atomicAdd(&A32[idx >> 2], 1u << ((idx & 3) * 8));
        atomicAdd(&d1[r], 1.0f);
        atomicAdd(&rowcnt[r], 1);
    }
}

// ---------- exclusive prefix sum of rowcnt[4096] -> rowptr[4097] (single block) ----------
__global__ __launch_bounds__(256) void prefix4096(const int* __restrict__ rowcnt,
                                                  int* __restrict__ rowptr) {
    __shared__ int psum[256];
    int t = threadIdx.x;
    int loc[16];
    int s = 0;
    #pragma unroll
    for (int i = 0; i < 16; i++) { loc[i] = s; s += rowcnt[t * 16 + i]; }
    psum[t] = s;
    __syncthreads();
    if (t == 0) {
        int run = 0;
        for (int i = 0; i < 256; i++) { int v = psum[i]; psum[i] = run; run += v; }
        rowptr[4096] = run;
    }
    __syncthreads();
    int off = psum[t];
    #pragma unroll
    for (int i = 0; i < 16; i++) rowptr[t * 16 + i] = off + loc[i];
}

// ---------- scatter edges into CSR colidx ----------
__global__ void scatter_edges(const int* __restrict__ ei, const int* __restrict__ rowptr,
                              int* __restrict__ cursor, int* __restrict__ colidx) {
    int e = blockIdx.x * blockDim.x + threadIdx.x;
    if (e < NE) {
        int r = ei[e];
        int p = atomicAdd(&cursor[r], 1);
        colidx[rowptr[r] + p] = ei[NE + e];
    }
}

// ---------- u8 -> transposed bf16 Atb (tiled) ----------
__global__ __launch_bounds__(256) void convert_t(const unsigned char* __restrict__ A8,
                                                 bf16* __restrict__ Atb) {
    __shared__ unsigned char tile[64][68];
    int t = threadIdx.x;
    int r = t >> 2, c16 = (t & 3) * 16;
    int gr = blockIdx.y * 64 + r;
    int gc = blockIdx.x * 64 + c16;
    union { uint4 q; unsigned char b[16]; } v;
    v.q = *(const uint4*)(A8 + (size_t)gr * NN + gc);
    #pragma unroll
    for (int i = 0; i < 16; i++) tile[r][c16 + i] = v.b[i];
    __syncthreads();
    int tr = t >> 2;
    int rr = (t & 3) * 16;
    bf16 ot[16];
    #pragma unroll
    for (int i = 0; i < 16; i++) ot[i] = __float2bfloat16((float)tile[rr + i][tr]);
    bf16* dt = Atb + (size_t)(blockIdx.x * 64 + tr) * NN + blockIdx.y * 64 + rr;
    *(uint4*)dt = ((uint4*)ot)[0];
    *(uint4*)(dt + 8) = ((uint4*)ot)[1];
}

// ---------- sparse matvec via edge list ----------
__global__ void spmv_edge(const int* __restrict__ ei, const float* __restrict__ vin,
                          float* __restrict__ vout) {
    int e = blockIdx.x * blockDim.x + threadIdx.x;
    if (e < NE) atomicAdd(&vout[ei[e]], vin[ei[NE + e]]);
}

// ---------- score = tanh(pw0 * (x . transform) + pw1 * degree) ----------
__global__ void score_kernel(const float* __restrict__ x, const float* __restrict__ tr,
                             const float* __restrict__ d1, const float* __restrict__ d2,
                             const float* __restrict__ d3, const float* __restrict__ fw,
                             const float* __restrict__ pw, float* __restrict__ score) {
    int gtid = blockIdx.x * blockDim.x + threadIdx.x;
    int node = gtid >> 6;
    int lane = gtid & 63;
    if (node >= NN) return;
    const float* xr = x + (size_t)node * CH;
    float s = 0.f;
    #pragma unroll
    for (int q = 0; q < CH; q += 64) s += xr[q + lane] * tr[q + lane];
    #pragma unroll
    for (int off = 32; off > 0; off >>= 1) s += __shfl_down(s, off);
    if (lane == 0) {
        float deg = fw[0] + fw[1] * d1[node] + fw[2] * d2[node] + fw[3] * d3[node];
        score[node] = tanhf(pw[0] * s + pw[1] * deg);
    }
}

// ---------- stable descending argsort: one block per node i ----------
__global__ __launch_bounds__(256) void rank_kernel(const float* __restrict__ score,
                                                   int* __restrict__ perm,
                                                   float* __restrict__ score_perm,
                                                   float* __restrict__ out_perm,
                                                   float* __restrict__ out_score) {
    __shared__ int wsum[4];
    int i = blockIdx.x;
    int t = threadIdx.x;
    float si = score[i];
    int cnt = 0;
    #pragma unroll
    for (int it = 0; it < NN / 4 / 256; it++) {
        int j4 = it * 256 + t;
        float4 s4 = reinterpret_cast<const float4*>(score)[j4];
        int j = j4 * 4;
        cnt += (int)((s4.x > si) | ((s4.x == si) & (j + 0 < i)));
        cnt += (int)((s4.y > si) | ((s4.y == si) & (j + 1 < i)));
        cnt += (int)((s4.z > si) | ((s4.z == si) & (j + 2 < i)));
        cnt += (int)((s4.w > si) | ((s4.w == si) & (j + 3 < i)));
    }
    #pragma unroll
    for (int off = 32; off > 0; off >>= 1) cnt += __shfl_down(cnt, off);
    if ((t & 63) == 0) wsum[t >> 6] = cnt;
    __syncthreads();
    if (t == 0) {
        int r = wsum[0] + wsum[1] + wsum[2] + wsum[3];
        if (r < KSEL) {
            perm[r] = i;
            score_perm[r] = si;
            out_perm[r] = (float)i;
            out_score[r] = si;
        }
    }
}

// ---------- Bt2 = Atb[perm, :]  (== (A[:,perm])^T, 2048 x 4096 bf16) ----------
__global__ void bt2_gather(const bf16* __restrict__ Atb, const int* __restrict__ perm,
                           bf16* __restrict__ Bt2) {
    int idx = blockIdx.x * blockDim.x + threadIdx.x;
    int r = idx >> 9;
    int off = (idx & 511) * 8;
    *(uint4*)(Bt2 + (size_t)r * NN + off) =
        *(const uint4*)(Atb + (size_t)perm[r] * NN + off);
}

// ===== SpGEMM: A2[r,:] = Σ_{k in adj(perm[r])} A[k,:]  (counts; one block/row) =====
__global__ __launch_bounds__(256) void spgemm_A2(const int* __restrict__ rowptr,
                                                 const int* __restrict__ colidx,
                                                 const int* __restrict__ perm,
                                                 bf16* __restrict__ A2b) {
    __shared__ float acc[NN];
    __shared__ int nbK[512];
    int t = threadIdx.x;
    int r = blockIdx.x;
    int pr = perm[r];
    #pragma unroll
    for (int i = t; i < NN / 4; i += 256)
        *(float4*)&acc[i * 4] = float4{0.f, 0.f, 0.f, 0.f};
    int s = rowptr[pr], e2 = rowptr[pr + 1];
    int deg = e2 - s;
    for (int base = 0; base < deg; base += 512) {
        int n = min(512, deg - base);
        __syncthreads();
        for (int i = t; i < n; i += 256) nbK[i] = colidx[s + base + i];
        __syncthreads();
        int wave = t >> 6, lane = t & 63;
        for (int i = wave; i < n; i += 4) {
            int k = nbK[i];
            int ks = rowptr[k], ke = rowptr[k + 1];
            for (int j = ks + lane; j < ke; j += 64)
                atomicAdd(&acc[colidx[j]], 1.0f);
        }
    }
    __syncthreads();
    for (int i = t; i < NN / 8; i += 256) {
        union { uint4 q; unsigned short h[8]; } o;
        #pragma unroll
        for (int u = 0; u < 8; u++) {
            bf16 hb = __float2bfloat16(acc[i * 8 + u]);
            o.h[u] = *reinterpret_cast<unsigned short*>(&hb);
        }
        *(uint4*)(A2b + (size_t)r * NN + i * 8) = o.q;
    }
}

// ---------- G[r,:] = w3*A2[r,:] + w2*A[pr,:] + w1*e_pr  (in place; A from u8) ----------
__global__ void fuse_G(const unsigned char* __restrict__ A8, const int* __restrict__ perm,
                       const float* __restrict__ fw, bf16* __restrict__ A2b) {
    int idx = blockIdx.x * blockDim.x + threadIdx.x;
    int r = idx >> 9;
    int kt = (idx & 511) * 8;
    int pr = perm[r];
    float w1 = fw[1], w2 = fw[2], w3 = fw[3];
    union { uint4 q; unsigned short s[8]; } ua, uo;
    union { uint2 d; unsigned char b[8]; } ub;
    ua.q = *(const uint4*)(A2b + (size_t)r * NN + kt);
    ub.d = *(const uint2*)(A8 + (size_t)pr * NN + kt);
    #pragma unroll
    for (int i = 0; i < 8; i++) {
        float g = w3 * bf2f(ua.s[i]) + w2 * (float)ub.b[i] + ((kt + i) == pr ? w1 : 0.f);
        bf16 h = __float2bfloat16(g);
        uo.s[i] = *reinterpret_cast<unsigned short*>(&h);
    }
    *(uint4*)(A2b + (size_t)r * NN + kt) = uo.q;
}

// ===== GEMM2: M_pool = G * Bt2^T + w0*I  (128x64 tile, clean epilogue) =====
__global__ __launch_bounds__(256) void gemm2_mfma(const bf16* __restrict__ Gb,
                                                  const bf16* __restrict__ Bt2,
                                                  const float* __restrict__ fw,
                                                  float* __restrict__ Mpool) {
    __shared__ bf16 As[128 * 32];
    __shared__ bf16 Bs[64 * 32];
    int tid = threadIdx.x;
    int wave = tid >> 6;
    int ln = tid & 15;
    int kq = (tid >> 4) & 3;
    int wr = wave >> 1, wc = wave & 1;
    int row0 = blockIdx.y * 128, col0 = blockIdx.x * 64;

    int srow = tid >> 2;
    int sk = (tid & 3) * 8;
    const bf16* agp0 = Gb + (size_t)(row0 + srow) * NN + sk;
    const bf16* agp1 = Gb + (size_t)(row0 + 64 + srow) * NN + sk;
    const bf16* bgp0 = Bt2 + (size_t)(col0 + srow) * NN + sk;
    bf16* asl0 = As + wave * 512;
    bf16* asl1 = As + 2048 + wave * 512;
    bf16* bsl0 = Bs + wave * 512;

    f32x4 acc[4][2] = {};
    for (int k0 = 0; k0 < NN; k0 += 32) {
        GLOAD_LDS16(agp0 + k0, asl0);
        GLOAD_LDS16(agp1 + k0, asl1);
        GLOAD_LDS16(bgp0 + k0, bsl0);
        __syncthreads();
        bf16x8 a[4], b[2];
        #pragma unroll
        for (int m = 0; m < 4; m++)
            a[m] = *(const bf16x8*)(As + (wr * 64 + m * 16 + ln) * 32 + kq * 8);
        #pragma unroll
        for (int n = 0; n < 2; n++)
            b[n] = *(const bf16x8*)(Bs + (wc * 32 + n * 16 + ln) * 32 + kq * 8);
        #pragma unroll
        for (int m = 0; m < 4; m++)
            #pragma unroll
            for (int n = 0; n < 2; n++)
                acc[m][n] = __builtin_amdgcn_mfma_f32_16x16x32_bf16(a[m], b[n], acc[m][n], 0, 0, 0);
        __syncthreads();
    }
    float w0 = fw[0];
    #pragma unroll
    for (int m = 0; m < 4; m++) {
        #pragma unroll
        for (int n = 0; n < 2; n++) {
            int c = col0 + wc * 32 + n * 16 + ln;
            #pragma unroll
            for (int j = 0; j < 4; j++) {
                int r = row0 + wr * 64 + m * 16 + kq * 4 + j;
                float mv = acc[m][n][j];
                if (r == c) mv += w0;
                Mpool[(size_t)r * KSEL + c] = mv;
            }
        }
    }
}

// ---------- x_out = x[perm] * score[perm] ----------
__global__ void xout_kernel(const float* __restrict__ x, const int* __restrict__ perm,
                            const float* __restrict__ score_perm, float* __restrict__ out) {
    int idx = blockIdx.x * blockDim.x + threadIdx.x;
    int r = idx >> 8;
    out[idx] = x[(size_t)perm[r] * CH + (idx & 255)] * score_perm[r];
}

extern "C" void kernel_launch(void* const* d_in, const int* in_sizes, int n_in,
                              void* d_out, int out_size, void* d_ws, size_t ws_size,
                              hipStream_t stream) {
    const float* x  = (const float*)d_in[0];
    const int*   ei = (const int*)d_in[1];
    const float* tr = (const float*)d_in[2];
    const float* fw = (const float*)d_in[3];
    const float* pw = (const float*)d_in[4];

    float* out       = (float*)d_out;
    float* out_x     = out;
    float* out_M     = out + (size_t)KSEL * CH;
    float* out_perm  = out_M + (size_t)KSEL * KSEL;
    float* out_score = out_perm + KSEL;

    char* ws = (char*)d_ws;
    unsigned char* A8  = (unsigned char*)ws;           // [0,16Mi)  u8 counts (kept live)
    unsigned int*  A32 = (unsigned int*)ws;
    bf16* Atb = (bf16*)(ws + 16777216);                // [16Mi,48Mi) A^T bf16
    bf16* A2b = (bf16*)(ws + 50331648);                // [48Mi,64Mi) A2[perm,:] -> G in place
    bf16* Bt2 = (bf16*)(ws + 67108864);                // [64Mi,80Mi) (A[:,perm])^T
    int* rowptr = (int*)(ws + 83886080);               // [80Mi) 4097 ints
    int* rowcnt = (int*)(ws + 83886080 + 32768);       // 4096 ints
    int* cursor = (int*)(ws + 83886080 + 65536);       // 4096 ints
    int* colidx = (int*)(ws + 83886080 + 131072);      // 131072 ints
    float* vec = (float*)(ws + 84934656);              // [81Mi, +80KiB)
    float* d1 = vec;
    float* d2 = vec + 4096;
    float* d3 = vec + 8192;
    float* score = vec + 12288;
    int*   perm = (int*)(vec + 16384);
    float* score_perm = vec + 18432;

    hipMemsetAsync(A32, 0, (size_t)NN * NN, stream);
    hipMemsetAsync(rowcnt, 0, 65536, stream);          // rowcnt + cursor
    hipMemsetAsync(vec, 0, 81920, stream);

    build_A<<<NE / 256, 256, 0, stream>>>(ei, A32, d1, rowcnt);
    prefix4096<<<1, 256, 0, stream>>>(rowcnt, rowptr);
    scatter_edges<<<NE / 256, 256, 0, stream>>>(ei, rowptr, cursor, colidx);
    spmv_edge<<<NE / 256, 256, 0, stream>>>(ei, d1, d2);
    spmv_edge<<<NE / 256, 256, 0, stream>>>(ei, d2, d3);
    score_kernel<<<(NN * 64) / 256, 256, 0, stream>>>(x, tr, d1, d2, d3, fw, pw, score);
    rank_kernel<<<NN, 256, 0, stream>>>(score, perm, score_perm, out_perm, out_score);
    convert_t<<<dim3(64, 64), 256, 0, stream>>>(A8, Atb);
    bt2_gather<<<(KSEL * 512) / 256, 256, 0, stream>>>(Atb, perm, Bt2);
    spgemm_A2<<<KSEL, 256, 0, stream>>>(rowptr, colidx, perm, A2b);
    fuse_G<<<(KSEL * 512) / 256, 256, 0, stream>>>(A8, perm, fw, A2b);
    gemm2_mfma<<<dim3(KSEL / 64, KSEL / 128), 256, 0, stream>>>(A2b, Bt2, fw, out_M);
    xout_kernel<<<(KSEL * CH) / 256, 256, 0, stream>>>(x, perm, score_perm, out_x);
}